// Round 8
// baseline (564.671 us; speedup 1.0000x reference)
//
#include <hip/hip_runtime.h>
#include <hip/hip_bf16.h>
#include <hip/hip_fp16.h>

// GCN: h1 = relu(gcn(x,W1,b1)); h2 = relu(gcn(h1,W2,b2));
// pooled = segment_sum(h2, batch); out = sigmoid(pooled@Wc + bc)
// R13 NEUTRAL: agg not issue-bound. R14 NEUTRAL: per-node sort useless.
// R15-17 FAILED (1384us): bin-sweep agg hit byte floor (FETCH 126MB) but
//   ~0.1 outstanding req/wave -> latency-starved. TLP >> locality here.
//   BANKED: hipcc lowers atomicAdd(float*) to ~200cyc CAS; use unsafeAtomicAdd.
// R18 NEUTRAL: native fp atomics in bin_scatter/pool moved nothing ->
//   preprocessing tail is NOT fp-atomic-bound.
// R19: byte attack on both fronts. (1) agg: nt-load meta, nt-store Out ->
//   stop streams evicting Y from L2 (26+50MB/dispatch churn vs 25.6MB Y).
//   (2) H fp16 end-to-end: agg writes fp16 (WRITE 50->25), gemm2 reads fp16
//   A directly, pool reads fp16 (~100MB saved). (3) bin_scatter ->
//   bin_sort_csr: LDS counting-sort by cl (R15-verified pattern), in-place
//   sequential write-back, exact CSR offs/cnt; kills 64MB padded-bucket
//   scattered writes. Pred: agg 118->95-110 (FETCH 300-340, WRITE 25),
//   total 545->460-500. Falsif: FETCH flat => nt no-op; total -agg-only =>
//   tail is launch-gaps -> fuse next.
// R19b: resubmit verbatim — container failed twice (infra), no counters.
//   Audit found no crash-capable defect (R14 proved 73.7KB dyn LDS OK;
//   in-place sort race-free; CSR bounds checked).

#define FEAT 128
#define OUTC 64
#define NB_SHIFT 8
#define BINSZ 256      // nodes per bin
#define CAP 9216       // per-bin edge capacity
#define TILE_A 8192    // edges per phase-A block
#define CNT_STRIDE 16  // binCnt padding: one counter per 64B line
#define LDW 136        // padded W^T row stride (halves)

typedef _Float16 half8 __attribute__((ext_vector_type(8)));
typedef float    f32x4 __attribute__((ext_vector_type(4)));
typedef int      iv2  __attribute__((ext_vector_type(2)));
typedef int      iv4  __attribute__((ext_vector_type(4)));

// ---- Phase A: bin edges by col>>8 -----------------------------------------
__global__ __launch_bounds__(256) void bin_edges(const int* __restrict__ ei,
                                                 const float* __restrict__ ew,
                                                 int* __restrict__ binCnt,
                                                 int2* __restrict__ binned,
                                                 int E, int nbins) {
    __shared__ int hist[512];
    __shared__ int base[512];
    int tid = threadIdx.x;
    int e0 = blockIdx.x * TILE_A;
    for (int i = tid; i < nbins; i += 256) hist[i] = 0;
    __syncthreads();
    for (int i = 0; i < TILE_A; i += 256) {
        int e = e0 + i + tid;
        if (e < E) atomicAdd(&hist[ei[E + e] >> NB_SHIFT], 1);
    }
    __syncthreads();
    for (int i = tid; i < nbins; i += 256) {
        int h = hist[i];
        base[i] = (h > 0) ? atomicAdd(&binCnt[i * CNT_STRIDE], h) : 0;
        hist[i] = 0;
    }
    __syncthreads();
    for (int i = 0; i < TILE_A; i += 256) {
        int e = e0 + i + tid;
        if (e < E) {
            int col = ei[E + e];
            int row = ei[e];
            float w = ew[e];
            int b  = col >> NB_SHIFT;
            int lp = atomicAdd(&hist[b], 1);
            int pos = base[b] + lp;
            if (pos < CAP) {
                int cl = col & (BINSZ - 1);
                binned[(size_t)b * CAP + pos] = make_int2((cl << 24) | row, __float_as_int(w));
            }
        }
    }
}

// ---- Phase B: LDS counting-sort by target cl -> exact CSR, in-place --------
// R19: replaces padded-bucket scatter. Sorted stream written back SEQUENTIAL
// (coalesced) into the same bin region; offs[node]=b*CAP+kb[cl], cnt exact.
__global__ __launch_bounds__(256) void bin_sort_csr(int2* __restrict__ binned,
                                                    const int* __restrict__ binCnt,
                                                    int* __restrict__ offs,
                                                    int* __restrict__ cnt,
                                                    float* __restrict__ dinv, int N) {
    extern __shared__ int2 sE[];          // CAP entries = 73728 B dynamic
    __shared__ float dsum[BINSZ];
    __shared__ int kh[BINSZ], kb[BINSZ], ksc[BINSZ];
    int tid = threadIdx.x, b = blockIdx.x;
    int node0 = b << NB_SHIFT;
    dsum[tid] = 0.f;
    kh[tid] = 0;
    __syncthreads();
    int ne = min(binCnt[b * CNT_STRIDE], CAP);
    int2* src = binned + (size_t)b * CAP;
    // pass 1: per-target histogram + weighted degree
    for (int i = tid; i < ne; i += 256) {
        int2 m = src[i];
        int cl = ((unsigned)m.x) >> 24;
        atomicAdd(&kh[cl], 1);
        unsafeAtomicAdd(&dsum[cl], __int_as_float(m.y));
    }
    __syncthreads();
    // exclusive scan (Hillis-Steele over 256 == blockDim, R15-verified)
    int v = kh[tid];
    ksc[tid] = v;
    __syncthreads();
    for (int off = 1; off < BINSZ; off <<= 1) {
        int t = (tid >= off) ? ksc[tid - off] : 0;
        __syncthreads();
        ksc[tid] += t;
        __syncthreads();
    }
    kb[tid] = ksc[tid] - v;
    kh[tid] = 0;
    __syncthreads();
    // pass 2: scatter into LDS at sorted position; pack w as half2 here
    for (int i = tid; i < ne; i += 256) {
        int2 m = src[i];
        int cl = ((unsigned)m.x) >> 24;
        int p = kb[cl] + atomicAdd(&kh[cl], 1);
        unsigned short hs = __half_as_ushort(__float2half(__int_as_float(m.y)));
        sE[p] = make_int2(m.x & 0xFFFFFF, (int)hs | ((int)hs << 16));
    }
    __syncthreads();
    // pass 3: sequential coalesced write-back, in place
    for (int i = tid; i < ne; i += 256) src[i] = sE[i];
    int node = node0 + tid;
    if (node < N) {
        offs[node] = b * CAP + kb[tid];
        cnt[node]  = kh[tid];
        dinv[node] = rsqrtf(1.0f + dsum[tid]);
    }
}

// ---- one-time padded W^T fp16 prep (row stride LDW) ------------------------
__global__ void wt_prep(const float* __restrict__ W, _Float16* __restrict__ Wt) {
    int i = blockIdx.x * 256 + threadIdx.x;   // i < 16384
    int n = i >> 7, k = i & 127;
    Wt[(size_t)n * LDW + k] = (_Float16)W[(size_t)k * FEAT + n];
}

// ---- Y(fp16) = dinv[:,None]*(X @ W) via MFMA; TIn = float or __half --------
template<typename TIn>
__global__ __launch_bounds__(256) void gemm_mfma(const TIn* __restrict__ X,
                                                 const _Float16* __restrict__ Wt,
                                                 const float* __restrict__ dinv,
                                                 __half* __restrict__ Y, int N) {
    __shared__ _Float16 sWt[FEAT * LDW];   // 34816 B
    int tid  = threadIdx.x;
    int row0 = blockIdx.x * 128;
    {
        const int4* src = (const int4*)Wt;
        int4* dst = (int4*)sWt;
        for (int i = tid; i < (FEAT * LDW) / 8; i += 256) dst[i] = src[i];
    }
    __syncthreads();

    int wave = tid >> 6;
    int lane = tid & 63;
    int m    = lane & 15;
    int quad = lane >> 4;

    f32x4 acc[2][8];
    #pragma unroll
    for (int rt = 0; rt < 2; ++rt)
        #pragma unroll
        for (int ct = 0; ct < 8; ++ct)
            acc[rt][ct] = (f32x4){0.f, 0.f, 0.f, 0.f};

    int rowA[2];
    rowA[0] = min(row0 + wave * 32 + m, N - 1);
    rowA[1] = min(row0 + wave * 32 + 16 + m, N - 1);

    #pragma unroll
    for (int kt = 0; kt < 4; ++kt) {
        int k0 = kt * 32;
        half8 a[2];
        #pragma unroll
        for (int rt = 0; rt < 2; ++rt) {
            if constexpr (sizeof(TIn) == 4) {
                const float4* p = (const float4*)((const float*)X + (size_t)rowA[rt] * FEAT + k0 + quad * 8);
                float4 f0 = p[0], f1 = p[1];
                half8 h;
                h[0] = (_Float16)f0.x; h[1] = (_Float16)f0.y;
                h[2] = (_Float16)f0.z; h[3] = (_Float16)f0.w;
                h[4] = (_Float16)f1.x; h[5] = (_Float16)f1.y;
                h[6] = (_Float16)f1.z; h[7] = (_Float16)f1.w;
                a[rt] = h;
            } else {
                a[rt] = *(const half8*)((const _Float16*)X + (size_t)rowA[rt] * FEAT + k0 + quad * 8);
            }
        }
        #pragma unroll
        for (int ct = 0; ct < 8; ++ct) {
            half8 b = *(const half8*)&sWt[(ct * 16 + m) * LDW + k0 + quad * 8];
            acc[0][ct] = __builtin_amdgcn_mfma_f32_16x16x32_f16(a[0], b, acc[0][ct], 0, 0, 0);
            acc[1][ct] = __builtin_amdgcn_mfma_f32_16x16x32_f16(a[1], b, acc[1][ct], 0, 0, 0);
        }
    }

    #pragma unroll
    for (int rt = 0; rt < 2; ++rt) {
        int lr0 = wave * 32 + rt * 16 + quad * 4;
        #pragma unroll
        for (int r = 0; r < 4; ++r) {
            int gr = row0 + lr0 + r;
            if (gr < N) {
                float d = dinv[gr];
                #pragma unroll
                for (int ct = 0; ct < 8; ++ct)
                    Y[(size_t)gr * FEAT + ct * 16 + m] = __float2half(d * acc[rt][ct][r]);
            }
        }
    }
}

// ---- per-node aggregation (CSR): 4 rows/gather, nt meta/out, fp16 out ------
// wave = 1 node; 4 replica groups of 16 lanes. Group g handles edge slots
// {t+g, t+4+g}; lane (g, fl) loads int4 = 8 fp16 feats of its group's row.
// nt-load meta + nt-store Out keep L2 reserved for Y gather reuse (R19).
__global__ __launch_bounds__(256) void agg_kernel(const __half* __restrict__ Y,
                                                  const int2* __restrict__ elist,
                                                  const int* __restrict__ offs,
                                                  const int* __restrict__ cnt,
                                                  const float* __restrict__ dinv,
                                                  const float* __restrict__ bias,
                                                  __half* __restrict__ Out, int N) {
    int node = blockIdx.x * 4 + (threadIdx.x >> 6);
    int lane = threadIdx.x & 63;
    if (node >= N) return;
    int grp = lane >> 4;       // replica / edge slot within group-of-4
    int fl  = lane & 15;       // feature block: feats [fl*8, fl*8+8)
    int c = cnt[node];
    const iv2* meta = (const iv2*)(elist + offs[node]);

    __half2 z = __floats2half2_rn(0.f, 0.f);
    __half2 a0 = z, a1 = z, a2 = z, a3 = z;
    __half2 b0 = z, b1 = z, b2 = z, b3 = z;

    // self-loop term (weight 1): only replica group 0 contributes it
    if (grp == 0) {
        int4 sv = ((const int4*)(Y + (size_t)node * FEAT))[fl];
        a0 = *(const __half2*)&sv.x; a1 = *(const __half2*)&sv.y;
        a2 = *(const __half2*)&sv.z; a3 = *(const __half2*)&sv.w;
    }

    for (int t = 0; t < c; t += 8) {
        int eA = t + grp;
        int eB = t + 4 + grp;
        iv2 mA = (eA < c) ? __builtin_nontemporal_load(meta + eA) : (iv2){node, 0};
        iv2 mB = (eB < c) ? __builtin_nontemporal_load(meta + eB) : (iv2){node, 0};
        int4 vA = *(const int4*)(Y + (size_t)mA.x * FEAT + fl * 8);
        int4 vB = *(const int4*)(Y + (size_t)mB.x * FEAT + fl * 8);
        int wAi = mA.y, wBi = mB.y;
        __half2 wA = *(const __half2*)&wAi;
        __half2 wB = *(const __half2*)&wBi;
        a0 = __hfma2(wA, *(const __half2*)&vA.x, a0);
        a1 = __hfma2(wA, *(const __half2*)&vA.y, a1);
        a2 = __hfma2(wA, *(const __half2*)&vA.z, a2);
        a3 = __hfma2(wA, *(const __half2*)&vA.w, a3);
        b0 = __hfma2(wB, *(const __half2*)&vB.x, b0);
        b1 = __hfma2(wB, *(const __half2*)&vB.y, b1);
        b2 = __hfma2(wB, *(const __half2*)&vB.z, b2);
        b3 = __hfma2(wB, *(const __half2*)&vB.w, b3);
    }

    float2 F0 = __half22float2(a0), F1 = __half22float2(a1);
    float2 F2 = __half22float2(a2), F3 = __half22float2(a3);
    {
        float2 t0 = __half22float2(b0), t1 = __half22float2(b1);
        float2 t2 = __half22float2(b2), t3 = __half22float2(b3);
        F0.x += t0.x; F0.y += t0.y; F1.x += t1.x; F1.y += t1.y;
        F2.x += t2.x; F2.y += t2.y; F3.x += t3.x; F3.y += t3.y;
    }
    float f[8] = {F0.x, F0.y, F1.x, F1.y, F2.x, F2.y, F3.x, F3.y};
    #pragma unroll
    for (int i = 0; i < 8; ++i) {
        f[i] += __shfl_xor(f[i], 16);
        f[i] += __shfl_xor(f[i], 32);
    }
    if (grp == 0) {
        float d = dinv[node];
        int c0 = fl * 8;
        float4 bo0 = *(const float4*)(bias + c0);
        float4 bo1 = *(const float4*)(bias + c0 + 4);
        __half2 p01 = __floats2half2_rn(fmaxf(d * f[0] + bo0.x, 0.f), fmaxf(d * f[1] + bo0.y, 0.f));
        __half2 p23 = __floats2half2_rn(fmaxf(d * f[2] + bo0.z, 0.f), fmaxf(d * f[3] + bo0.w, 0.f));
        __half2 p45 = __floats2half2_rn(fmaxf(d * f[4] + bo1.x, 0.f), fmaxf(d * f[5] + bo1.y, 0.f));
        __half2 p67 = __floats2half2_rn(fmaxf(d * f[6] + bo1.z, 0.f), fmaxf(d * f[7] + bo1.w, 0.f));
        iv4 ov = { *(int*)&p01, *(int*)&p23, *(int*)&p45, *(int*)&p67 };
        __builtin_nontemporal_store(ov, (iv4*)(Out + (size_t)node * FEAT + c0));
    }
}

// ---- pooling (batch sorted): fp16 nt reads, fp32 accumulate ----------------
__global__ void pool_kernel(const __half* __restrict__ H, const int* __restrict__ batch,
                            float* __restrict__ pooled, int N, int chunk) {
    int f  = threadIdx.x;
    int n0 = blockIdx.x * chunk;
    if (n0 >= N) return;
    int n1 = min(n0 + chunk, N);
    float acc = 0.f;
    int cur = batch[n0];
    for (int n = n0; n < n1; ++n) {
        int g = batch[n];
        if (g != cur) {
            unsafeAtomicAdd(&pooled[cur * FEAT + f], acc);
            acc = 0.f;
            cur = g;
        }
        unsigned short us = __builtin_nontemporal_load((const unsigned short*)(H + (size_t)n * FEAT + f));
        acc += __half2float(__ushort_as_half(us));
    }
    unsafeAtomicAdd(&pooled[cur * FEAT + f], acc);
}

// ---- classifier ------------------------------------------------------------
__global__ void classify_kernel(const float* __restrict__ pooled, const float* __restrict__ Wc,
                                const float* __restrict__ bc, float* __restrict__ out) {
    int g = blockIdx.x;
    int c = threadIdx.x;
    float acc = bc[c];
    const float* pr = pooled + g * FEAT;
    for (int k = 0; k < FEAT; ++k) acc += pr[k] * Wc[k * OUTC + c];
    out[g * OUTC + c] = 1.0f / (1.0f + expf(-acc));
}

extern "C" void kernel_launch(void* const* d_in, const int* in_sizes, int n_in,
                              void* d_out, int out_size, void* d_ws, size_t ws_size,
                              hipStream_t stream) {
    const float* x     = (const float*)d_in[0];
    const int*   ei    = (const int*)d_in[1];
    const float* ew    = (const float*)d_in[2];
    const int*   batch = (const int*)d_in[3];
    const float* W1    = (const float*)d_in[4];
    const float* b1    = (const float*)d_in[5];
    const float* W2    = (const float*)d_in[6];
    const float* b2    = (const float*)d_in[7];
    const float* Wc    = (const float*)d_in[8];
    const float* bc    = (const float*)d_in[9];
    float* out = (float*)d_out;

    const int N = in_sizes[0] / FEAT;
    const int E = in_sizes[2];
    const int G = out_size / OUTC;
    const int nbins = (N + BINSZ - 1) / BINSZ;

    char* w = (char*)d_ws;
    size_t off = 0;
    auto alloc = [&](size_t bytes) {
        void* p = w + off;
        off = (off + bytes + 255) & ~(size_t)255;
        return p;
    };
    float*     dinv   = (float*)alloc((size_t)N * 4);
    int*       cnt    = (int*)alloc((size_t)N * 4);
    int*       offs   = (int*)alloc((size_t)N * 4);
    int*       binCnt = (int*)alloc((size_t)nbins * CNT_STRIDE * 4);  // line-padded
    int2*      binned = (int2*)alloc((size_t)nbins * CAP * 8);  // ~28.8 MB (sorted in place)
    __half*    bufY   = (__half*)alloc((size_t)N * FEAT * 2);   // fp16 Y
    __half*    bufH   = (__half*)alloc((size_t)N * FEAT * 2);   // fp16 h (R19)
    float*     pooled = (float*)alloc((size_t)G * FEAT * 4);
    _Float16*  wt1    = (_Float16*)alloc((size_t)FEAT * LDW * 2);
    _Float16*  wt2    = (_Float16*)alloc((size_t)FEAT * LDW * 2);
    (void)ws_size;

    hipMemsetAsync(binCnt, 0, (size_t)nbins * CNT_STRIDE * 4, stream);
    hipMemsetAsync(pooled, 0, (size_t)G * FEAT * 4, stream);

    bin_edges<<<(E + TILE_A - 1) / TILE_A, 256, 0, stream>>>(ei, ew, binCnt, binned, E, nbins);
    bin_sort_csr<<<nbins, 256, (size_t)CAP * sizeof(int2), stream>>>(binned, binCnt, offs, cnt, dinv, N);
    wt_prep<<<64, 256, 0, stream>>>(W1, wt1);
    wt_prep<<<64, 256, 0, stream>>>(W2, wt2);

    const int gemm_blocks = (N + 127) / 128;
    const int agg_blocks  = (N + 3) / 4;

    gemm_mfma<float><<<gemm_blocks, 256, 0, stream>>>(x, wt1, dinv, bufY, N);
    agg_kernel<<<agg_blocks, 256, 0, stream>>>(bufY, binned, offs, cnt, dinv, b1, bufH, N);
    gemm_mfma<__half><<<gemm_blocks, 256, 0, stream>>>(bufH, wt2, dinv, bufY, N);
    agg_kernel<<<agg_blocks, 256, 0, stream>>>(bufY, binned, offs, cnt, dinv, b2, bufH, N);

    const int chunk = 128;
    pool_kernel<<<(N + chunk - 1) / chunk, FEAT, 0, stream>>>(bufH, batch, pooled, N, chunk);
    classify_kernel<<<G, OUTC, 0, stream>>>(pooled, Wc, bc, out);
}

// Round 9
// 510.709 us; speedup vs baseline: 1.1057x; 1.1057x over previous
//
#include <hip/hip_runtime.h>
#include <hip/hip_bf16.h>
#include <hip/hip_fp16.h>

// GCN: h1 = relu(gcn(x,W1,b1)); h2 = relu(gcn(h1,W2,b2));
// pooled = segment_sum(h2, batch); out = sigmoid(pooled@Wc + bc)
// R13/R14 NEUTRAL. R15-17 FAILED (latency-starved bin-sweep; TLP>>locality).
//   BANKED: atomicAdd(float*) = ~200cyc CAS; use unsafeAtomicAdd.
// R18 NEUTRAL: fp atomics weren't the tail.
// R19 REGRESSION (564.7): nt hints BACKFIRED — agg FETCH 380->407MB (+meta
//   size: nt evicts meta from L2 early -> HBM refetch), dur 118->127.
//   fp16 H GOOD (WRITE 50->25). CSR neutral. => revert nt, keep fp16+CSR.
// R20: bin_edges writes were ~8x amplified (8B scatter into 391 cursors,
//   ~21-edge runs from non-adjacent lanes). Fix: in-LDS tile counting-sort
//   by bin (histogram -> 512-scan -> reserve -> LDS scatter 64KB -> run-
//   coalesced writeback). w packed to half here; bin id in y high16.
//   Pred: agg back to ~118/380MB; total 564.7 -> ~430-470 if bin_edges was
//   ~140us (R12 note), ~545 if not (=> tail is gemm/pool/gaps, instrument).

#define FEAT 128
#define OUTC 64
#define NB_SHIFT 8
#define BINSZ 256      // nodes per bin
#define CAP 9216       // per-bin edge capacity
#define TILE_A 8192    // edges per phase-A block
#define CNT_STRIDE 16  // binCnt padding: one counter per 64B line
#define LDW 136        // padded W^T row stride (halves)

typedef _Float16 half8 __attribute__((ext_vector_type(8)));
typedef float    f32x4 __attribute__((ext_vector_type(4)));
typedef int      iv4  __attribute__((ext_vector_type(4)));

// ---- Phase A: bin edges by col>>8, LDS tile-sort, run-coalesced writes -----
__global__ __launch_bounds__(256) void bin_edges(const int* __restrict__ ei,
                                                 const float* __restrict__ ew,
                                                 int* __restrict__ binCnt,
                                                 int2* __restrict__ binned,
                                                 int E, int nbins) {
    extern __shared__ int2 sE[];          // TILE_A entries = 65536 B dynamic
    __shared__ int kh[512], kb[512], kc[512], kg[512], ksc[512];
    int tid = threadIdx.x;
    int e0 = blockIdx.x * TILE_A;
    kh[tid] = 0; kh[tid + 256] = 0;
    kc[tid] = 0; kc[tid + 256] = 0;
    __syncthreads();
    // pass 1: histogram by bin
    for (int i = 0; i < TILE_A; i += 256) {
        int e = e0 + i + tid;
        if (e < E) atomicAdd(&kh[ei[E + e] >> NB_SHIFT], 1);
    }
    __syncthreads();
    // inclusive scan over 512 (2 elems/thread, reg-buffered H-S)
    int v0 = kh[tid], v1 = kh[tid + 256];
    ksc[tid] = v0; ksc[tid + 256] = v1;
    __syncthreads();
    for (int off = 1; off < 512; off <<= 1) {
        int a0 = (tid >= off) ? ksc[tid - off] : 0;
        int a1 = (tid + 256 >= off) ? ksc[tid + 256 - off] : 0;
        __syncthreads();
        ksc[tid] += a0; ksc[tid + 256] += a1;
        __syncthreads();
    }
    kb[tid] = ksc[tid] - v0;
    kb[tid + 256] = ksc[tid + 256] - v1;
    // reserve global bases (one padded counter per bin)
    if (tid < nbins && v0 > 0) kg[tid] = atomicAdd(&binCnt[tid * CNT_STRIDE], v0);
    int t2 = tid + 256;
    if (t2 < nbins && v1 > 0) kg[t2] = atomicAdd(&binCnt[t2 * CNT_STRIDE], v1);
    __syncthreads();
    // pass 2: LDS scatter at sorted position; pack w->half, bin in y high16
    for (int i = 0; i < TILE_A; i += 256) {
        int e = e0 + i + tid;
        if (e < E) {
            int col = ei[E + e];
            int row = ei[e];
            unsigned short hs = __half_as_ushort(__float2half(ew[e]));
            int b = col >> NB_SHIFT;
            int p = kb[b] + atomicAdd(&kc[b], 1);
            int cl = col & (BINSZ - 1);
            sE[p] = make_int2((cl << 24) | row, (b << 16) | (int)hs);
        }
    }
    __syncthreads();
    // pass 3: run-coalesced writeback (consecutive lanes -> consecutive dst)
    int tot = ksc[511];
    for (int i = tid; i < tot; i += 256) {
        int2 m = sE[i];
        int b = ((unsigned)m.y) >> 16;
        int loc = kg[b] + (i - kb[b]);
        if (loc < CAP)
            binned[(size_t)b * CAP + loc] = make_int2(m.x, m.y & 0xFFFF);
    }
}

// ---- Phase B: LDS counting-sort by target cl -> exact CSR, in-place --------
__global__ __launch_bounds__(256) void bin_sort_csr(int2* __restrict__ binned,
                                                    const int* __restrict__ binCnt,
                                                    int* __restrict__ offs,
                                                    int* __restrict__ cnt,
                                                    float* __restrict__ dinv, int N) {
    extern __shared__ int2 sE[];          // CAP entries = 73728 B dynamic
    __shared__ float dsum[BINSZ];
    __shared__ int kh[BINSZ], kb[BINSZ], ksc[BINSZ];
    int tid = threadIdx.x, b = blockIdx.x;
    int node0 = b << NB_SHIFT;
    dsum[tid] = 0.f;
    kh[tid] = 0;
    __syncthreads();
    int ne = min(binCnt[b * CNT_STRIDE], CAP);
    int2* src = binned + (size_t)b * CAP;
    // pass 1: per-target histogram + weighted degree (w is half in y low16)
    for (int i = tid; i < ne; i += 256) {
        int2 m = src[i];
        int cl = ((unsigned)m.x) >> 24;
        atomicAdd(&kh[cl], 1);
        unsafeAtomicAdd(&dsum[cl], __half2float(__ushort_as_half((unsigned short)(m.y & 0xFFFF))));
    }
    __syncthreads();
    // exclusive scan (Hillis-Steele over 256 == blockDim)
    int v = kh[tid];
    ksc[tid] = v;
    __syncthreads();
    for (int off = 1; off < BINSZ; off <<= 1) {
        int t = (tid >= off) ? ksc[tid - off] : 0;
        __syncthreads();
        ksc[tid] += t;
        __syncthreads();
    }
    kb[tid] = ksc[tid] - v;
    kh[tid] = 0;
    __syncthreads();
    // pass 2: scatter into LDS at sorted position; duplicate half w -> half2
    for (int i = tid; i < ne; i += 256) {
        int2 m = src[i];
        int cl = ((unsigned)m.x) >> 24;
        int p = kb[cl] + atomicAdd(&kh[cl], 1);
        int hw = m.y & 0xFFFF;
        sE[p] = make_int2(m.x & 0xFFFFFF, hw | (hw << 16));
    }
    __syncthreads();
    // pass 3: sequential coalesced write-back, in place
    for (int i = tid; i < ne; i += 256) src[i] = sE[i];
    int node = node0 + tid;
    if (node < N) {
        offs[node] = b * CAP + kb[tid];
        cnt[node]  = kh[tid];
        dinv[node] = rsqrtf(1.0f + dsum[tid]);
    }
}

// ---- one-time padded W^T fp16 prep (row stride LDW) ------------------------
__global__ void wt_prep(const float* __restrict__ W, _Float16* __restrict__ Wt) {
    int i = blockIdx.x * 256 + threadIdx.x;   // i < 16384
    int n = i >> 7, k = i & 127;
    Wt[(size_t)n * LDW + k] = (_Float16)W[(size_t)k * FEAT + n];
}

// ---- Y(fp16) = dinv[:,None]*(X @ W) via MFMA; TIn = float or __half --------
template<typename TIn>
__global__ __launch_bounds__(256) void gemm_mfma(const TIn* __restrict__ X,
                                                 const _Float16* __restrict__ Wt,
                                                 const float* __restrict__ dinv,
                                                 __half* __restrict__ Y, int N) {
    __shared__ _Float16 sWt[FEAT * LDW];   // 34816 B
    int tid  = threadIdx.x;
    int row0 = blockIdx.x * 128;
    {
        const int4* src = (const int4*)Wt;
        int4* dst = (int4*)sWt;
        for (int i = tid; i < (FEAT * LDW) / 8; i += 256) dst[i] = src[i];
    }
    __syncthreads();

    int wave = tid >> 6;
    int lane = tid & 63;
    int m    = lane & 15;
    int quad = lane >> 4;

    f32x4 acc[2][8];
    #pragma unroll
    for (int rt = 0; rt < 2; ++rt)
        #pragma unroll
        for (int ct = 0; ct < 8; ++ct)
            acc[rt][ct] = (f32x4){0.f, 0.f, 0.f, 0.f};

    int rowA[2];
    rowA[0] = min(row0 + wave * 32 + m, N - 1);
    rowA[1] = min(row0 + wave * 32 + 16 + m, N - 1);

    #pragma unroll
    for (int kt = 0; kt < 4; ++kt) {
        int k0 = kt * 32;
        half8 a[2];
        #pragma unroll
        for (int rt = 0; rt < 2; ++rt) {
            if constexpr (sizeof(TIn) == 4) {
                const float4* p = (const float4*)((const float*)X + (size_t)rowA[rt] * FEAT + k0 + quad * 8);
                float4 f0 = p[0], f1 = p[1];
                half8 h;
                h[0] = (_Float16)f0.x; h[1] = (_Float16)f0.y;
                h[2] = (_Float16)f0.z; h[3] = (_Float16)f0.w;
                h[4] = (_Float16)f1.x; h[5] = (_Float16)f1.y;
                h[6] = (_Float16)f1.z; h[7] = (_Float16)f1.w;
                a[rt] = h;
            } else {
                a[rt] = *(const half8*)((const _Float16*)X + (size_t)rowA[rt] * FEAT + k0 + quad * 8);
            }
        }
        #pragma unroll
        for (int ct = 0; ct < 8; ++ct) {
            half8 b = *(const half8*)&sWt[(ct * 16 + m) * LDW + k0 + quad * 8];
            acc[0][ct] = __builtin_amdgcn_mfma_f32_16x16x32_f16(a[0], b, acc[0][ct], 0, 0, 0);
            acc[1][ct] = __builtin_amdgcn_mfma_f32_16x16x32_f16(a[1], b, acc[1][ct], 0, 0, 0);
        }
    }

    #pragma unroll
    for (int rt = 0; rt < 2; ++rt) {
        int lr0 = wave * 32 + rt * 16 + quad * 4;
        #pragma unroll
        for (int r = 0; r < 4; ++r) {
            int gr = row0 + lr0 + r;
            if (gr < N) {
                float d = dinv[gr];
                #pragma unroll
                for (int ct = 0; ct < 8; ++ct)
                    Y[(size_t)gr * FEAT + ct * 16 + m] = __float2half(d * acc[rt][ct][r]);
            }
        }
    }
}

// ---- per-node aggregation (CSR): 4 rows/gather, plain loads, fp16 out ------
__global__ __launch_bounds__(256) void agg_kernel(const __half* __restrict__ Y,
                                                  const int2* __restrict__ elist,
                                                  const int* __restrict__ offs,
                                                  const int* __restrict__ cnt,
                                                  const float* __restrict__ dinv,
                                                  const float* __restrict__ bias,
                                                  __half* __restrict__ Out, int N) {
    int node = blockIdx.x * 4 + (threadIdx.x >> 6);
    int lane = threadIdx.x & 63;
    if (node >= N) return;
    int grp = lane >> 4;       // replica / edge slot within group-of-4
    int fl  = lane & 15;       // feature block: feats [fl*8, fl*8+8)
    int c = cnt[node];
    const int2* meta = elist + offs[node];

    __half2 z = __floats2half2_rn(0.f, 0.f);
    __half2 a0 = z, a1 = z, a2 = z, a3 = z;
    __half2 b0 = z, b1 = z, b2 = z, b3 = z;

    // self-loop term (weight 1): only replica group 0 contributes it
    if (grp == 0) {
        int4 sv = ((const int4*)(Y + (size_t)node * FEAT))[fl];
        a0 = *(const __half2*)&sv.x; a1 = *(const __half2*)&sv.y;
        a2 = *(const __half2*)&sv.z; a3 = *(const __half2*)&sv.w;
    }

    for (int t = 0; t < c; t += 8) {
        int eA = t + grp;
        int eB = t + 4 + grp;
        int2 mA = (eA < c) ? meta[eA] : make_int2(node, 0);  // w=0 pad, safe row
        int2 mB = (eB < c) ? meta[eB] : make_int2(node, 0);
        int4 vA = *(const int4*)(Y + (size_t)mA.x * FEAT + fl * 8);
        int4 vB = *(const int4*)(Y + (size_t)mB.x * FEAT + fl * 8);
        __half2 wA = *(const __half2*)&mA.y;
        __half2 wB = *(const __half2*)&mB.y;
        a0 = __hfma2(wA, *(const __half2*)&vA.x, a0);
        a1 = __hfma2(wA, *(const __half2*)&vA.y, a1);
        a2 = __hfma2(wA, *(const __half2*)&vA.z, a2);
        a3 = __hfma2(wA, *(const __half2*)&vA.w, a3);
        b0 = __hfma2(wB, *(const __half2*)&vB.x, b0);
        b1 = __hfma2(wB, *(const __half2*)&vB.y, b1);
        b2 = __hfma2(wB, *(const __half2*)&vB.z, b2);
        b3 = __hfma2(wB, *(const __half2*)&vB.w, b3);
    }

    float2 F0 = __half22float2(a0), F1 = __half22float2(a1);
    float2 F2 = __half22float2(a2), F3 = __half22float2(a3);
    {
        float2 t0 = __half22float2(b0), t1 = __half22float2(b1);
        float2 t2 = __half22float2(b2), t3 = __half22float2(b3);
        F0.x += t0.x; F0.y += t0.y; F1.x += t1.x; F1.y += t1.y;
        F2.x += t2.x; F2.y += t2.y; F3.x += t3.x; F3.y += t3.y;
    }
    float f[8] = {F0.x, F0.y, F1.x, F1.y, F2.x, F2.y, F3.x, F3.y};
    #pragma unroll
    for (int i = 0; i < 8; ++i) {
        f[i] += __shfl_xor(f[i], 16);
        f[i] += __shfl_xor(f[i], 32);
    }
    if (grp == 0) {
        float d = dinv[node];
        int c0 = fl * 8;
        float4 bo0 = *(const float4*)(bias + c0);
        float4 bo1 = *(const float4*)(bias + c0 + 4);
        __half2 p01 = __floats2half2_rn(fmaxf(d * f[0] + bo0.x, 0.f), fmaxf(d * f[1] + bo0.y, 0.f));
        __half2 p23 = __floats2half2_rn(fmaxf(d * f[2] + bo0.z, 0.f), fmaxf(d * f[3] + bo0.w, 0.f));
        __half2 p45 = __floats2half2_rn(fmaxf(d * f[4] + bo1.x, 0.f), fmaxf(d * f[5] + bo1.y, 0.f));
        __half2 p67 = __floats2half2_rn(fmaxf(d * f[6] + bo1.z, 0.f), fmaxf(d * f[7] + bo1.w, 0.f));
        iv4 ov = { *(int*)&p01, *(int*)&p23, *(int*)&p45, *(int*)&p67 };
        *(iv4*)(Out + (size_t)node * FEAT + c0) = ov;
    }
}

// ---- pooling (batch sorted): fp16 reads, fp32 accumulate -------------------
__global__ void pool_kernel(const __half* __restrict__ H, const int* __restrict__ batch,
                            float* __restrict__ pooled, int N, int chunk) {
    int f  = threadIdx.x;
    int n0 = blockIdx.x * chunk;
    if (n0 >= N) return;
    int n1 = min(n0 + chunk, N);
    float acc = 0.f;
    int cur = batch[n0];
    for (int n = n0; n < n1; ++n) {
        int g = batch[n];
        if (g != cur) {
            unsafeAtomicAdd(&pooled[cur * FEAT + f], acc);
            acc = 0.f;
            cur = g;
        }
        acc += __half2float(H[(size_t)n * FEAT + f]);
    }
    unsafeAtomicAdd(&pooled[cur * FEAT + f], acc);
}

// ---- classifier ------------------------------------------------------------
__global__ void classify_kernel(const float* __restrict__ pooled, const float* __restrict__ Wc,
                                const float* __restrict__ bc, float* __restrict__ out) {
    int g = blockIdx.x;
    int c = threadIdx.x;
    float acc = bc[c];
    const float* pr = pooled + g * FEAT;
    for (int k = 0; k < FEAT; ++k) acc += pr[k] * Wc[k * OUTC + c];
    out[g * OUTC + c] = 1.0f / (1.0f + expf(-acc));
}

extern "C" void kernel_launch(void* const* d_in, const int* in_sizes, int n_in,
                              void* d_out, int out_size, void* d_ws, size_t ws_size,
                              hipStream_t stream) {
    const float* x     = (const float*)d_in[0];
    const int*   ei    = (const int*)d_in[1];
    const float* ew    = (const float*)d_in[2];
    const int*   batch = (const int*)d_in[3];
    const float* W1    = (const float*)d_in[4];
    const float* b1    = (const float*)d_in[5];
    const float* W2    = (const float*)d_in[6];
    const float* b2    = (const float*)d_in[7];
    const float* Wc    = (const float*)d_in[8];
    const float* bc    = (const float*)d_in[9];
    float* out = (float*)d_out;

    const int N = in_sizes[0] / FEAT;
    const int E = in_sizes[2];
    const int G = out_size / OUTC;
    const int nbins = (N + BINSZ - 1) / BINSZ;

    char* w = (char*)d_ws;
    size_t off = 0;
    auto alloc = [&](size_t bytes) {
        void* p = w + off;
        off = (off + bytes + 255) & ~(size_t)255;
        return p;
    };
    float*     dinv   = (float*)alloc((size_t)N * 4);
    int*       cnt    = (int*)alloc((size_t)N * 4);
    int*       offs   = (int*)alloc((size_t)N * 4);
    int*       binCnt = (int*)alloc((size_t)nbins * CNT_STRIDE * 4);  // line-padded
    int2*      binned = (int2*)alloc((size_t)nbins * CAP * 8);  // ~28.8 MB (sorted in place)
    __half*    bufY   = (__half*)alloc((size_t)N * FEAT * 2);   // fp16 Y
    __half*    bufH   = (__half*)alloc((size_t)N * FEAT * 2);   // fp16 h
    float*     pooled = (float*)alloc((size_t)G * FEAT * 4);
    _Float16*  wt1    = (_Float16*)alloc((size_t)FEAT * LDW * 2);
    _Float16*  wt2    = (_Float16*)alloc((size_t)FEAT * LDW * 2);
    (void)ws_size;

    hipMemsetAsync(binCnt, 0, (size_t)nbins * CNT_STRIDE * 4, stream);
    hipMemsetAsync(pooled, 0, (size_t)G * FEAT * 4, stream);

    bin_edges<<<(E + TILE_A - 1) / TILE_A, 256, (size_t)TILE_A * sizeof(int2), stream>>>(ei, ew, binCnt, binned, E, nbins);
    bin_sort_csr<<<nbins, 256, (size_t)CAP * sizeof(int2), stream>>>(binned, binCnt, offs, cnt, dinv, N);
    wt_prep<<<64, 256, 0, stream>>>(W1, wt1);
    wt_prep<<<64, 256, 0, stream>>>(W2, wt2);

    const int gemm_blocks = (N + 127) / 128;
    const int agg_blocks  = (N + 3) / 4;

    gemm_mfma<float><<<gemm_blocks, 256, 0, stream>>>(x, wt1, dinv, bufY, N);
    agg_kernel<<<agg_blocks, 256, 0, stream>>>(bufY, binned, offs, cnt, dinv, b1, bufH, N);
    gemm_mfma<__half><<<gemm_blocks, 256, 0, stream>>>(bufH, wt2, dinv, bufY, N);
    agg_kernel<<<agg_blocks, 256, 0, stream>>>(bufY, binned, offs, cnt, dinv, b2, bufH, N);

    const int chunk = 128;
    pool_kernel<<<(N + chunk - 1) / chunk, FEAT, 0, stream>>>(bufH, batch, pooled, N, chunk);
    classify_kernel<<<G, OUTC, 0, stream>>>(pooled, Wc, bc, out);
}

// Round 10
// 508.991 us; speedup vs baseline: 1.1094x; 1.0034x over previous
//
#include <hip/hip_runtime.h>
#include <hip/hip_bf16.h>
#include <hip/hip_fp16.h>

// GCN: h1 = relu(gcn(x,W1,b1)); h2 = relu(gcn(h1,W2,b2));
// pooled = segment_sum(h2, batch); out = sigmoid(pooled@Wc + bc)
// R13/R14 NEUTRAL. R15-17 FAILED (latency-starved bin-sweep; TLP>>locality).
//   BANKED: atomicAdd(float*) = ~200cyc CAS; use unsafeAtomicAdd.
// R18 NEUTRAL. R19 REGRESSION: nt hints evict-early (+meta refetch); fp16 H
//   GOOD (WRITE 50->25); CSR neutral-keep.
// R20 WIN (545.7->510.7): LDS tile-sort bin_edges. agg restored 115.6/381MB.
//   Ledger: agg 231 + tail ~280 across 10 dispatches, NONE visible in top-5;
//   bottom-up model says bin kernels ~25us each -> >100us unexplained.
// R21: (1) INSTRUMENT: split each agg into 2 node-range halves (~57us each,
//   no byte penalty, 12.5K blocks each) -> any tail kernel >57us surfaces in
//   top-5 with counters. (2) bin_edges/bin_sort_csr 256->512 threads (were
//   1.5 blocks/CU with 32-iter serial passes; halve iters, 2 blocks/CU).
//   Pred: agg ~55-62x4 (FETCH ~195 ea); total ~430-460 if bin kernels were
//   hogs, else ~500-515 + top-5 reveals the real hog. absmax unchanged.

#define FEAT 128
#define OUTC 64
#define NB_SHIFT 8
#define BINSZ 256      // nodes per bin
#define CAP 9216       // per-bin edge capacity
#define TILE_A 8192    // edges per phase-A block
#define CNT_STRIDE 16  // binCnt padding: one counter per 64B line
#define LDW 136        // padded W^T row stride (halves)

typedef _Float16 half8 __attribute__((ext_vector_type(8)));
typedef float    f32x4 __attribute__((ext_vector_type(4)));
typedef int      iv4  __attribute__((ext_vector_type(4)));

// ---- Phase A: bin edges by col>>8, LDS tile-sort, run-coalesced writes -----
// R21: 512 threads (was 256): halves per-pass iterations; LDS 74KB -> 2/CU.
__global__ __launch_bounds__(512) void bin_edges(const int* __restrict__ ei,
                                                 const float* __restrict__ ew,
                                                 int* __restrict__ binCnt,
                                                 int2* __restrict__ binned,
                                                 int E, int nbins) {
    extern __shared__ int2 sE[];          // TILE_A entries = 65536 B dynamic
    __shared__ int kh[512], kb[512], kc[512], kg[512], ksc[512];
    int tid = threadIdx.x;
    int e0 = blockIdx.x * TILE_A;
    kh[tid] = 0;
    kc[tid] = 0;
    __syncthreads();
    // pass 1: histogram by bin
    for (int i = 0; i < TILE_A; i += 512) {
        int e = e0 + i + tid;
        if (e < E) atomicAdd(&kh[ei[E + e] >> NB_SHIFT], 1);
    }
    __syncthreads();
    // inclusive scan over 512 (1 elem/thread H-S)
    int v = kh[tid];
    ksc[tid] = v;
    __syncthreads();
    for (int off = 1; off < 512; off <<= 1) {
        int a = (tid >= off) ? ksc[tid - off] : 0;
        __syncthreads();
        ksc[tid] += a;
        __syncthreads();
    }
    kb[tid] = ksc[tid] - v;
    // reserve global bases (one padded counter per bin)
    if (tid < nbins && v > 0) kg[tid] = atomicAdd(&binCnt[tid * CNT_STRIDE], v);
    __syncthreads();
    // pass 2: LDS scatter at sorted position; pack w->half, bin in y high16
    for (int i = 0; i < TILE_A; i += 512) {
        int e = e0 + i + tid;
        if (e < E) {
            int col = ei[E + e];
            int row = ei[e];
            unsigned short hs = __half_as_ushort(__float2half(ew[e]));
            int b = col >> NB_SHIFT;
            int p = kb[b] + atomicAdd(&kc[b], 1);
            int cl = col & (BINSZ - 1);
            sE[p] = make_int2((cl << 24) | row, (b << 16) | (int)hs);
        }
    }
    __syncthreads();
    // pass 3: run-coalesced writeback (consecutive lanes -> consecutive dst)
    int tot = ksc[511];
    for (int i = tid; i < tot; i += 512) {
        int2 m = sE[i];
        int b = ((unsigned)m.y) >> 16;
        int loc = kg[b] + (i - kb[b]);
        if (loc < CAP)
            binned[(size_t)b * CAP + loc] = make_int2(m.x, m.y & 0xFFFF);
    }
}

// ---- Phase B: LDS counting-sort by target cl -> exact CSR, in-place --------
// R21: 512 threads; scan done by tid<256 (BINSZ), passes stride 512.
__global__ __launch_bounds__(512) void bin_sort_csr(int2* __restrict__ binned,
                                                    const int* __restrict__ binCnt,
                                                    int* __restrict__ offs,
                                                    int* __restrict__ cnt,
                                                    float* __restrict__ dinv, int N) {
    extern __shared__ int2 sE[];          // CAP entries = 73728 B dynamic
    __shared__ float dsum[BINSZ];
    __shared__ int kh[BINSZ], kb[BINSZ], ksc[BINSZ];
    int tid = threadIdx.x, b = blockIdx.x;
    int node0 = b << NB_SHIFT;
    if (tid < BINSZ) { dsum[tid] = 0.f; kh[tid] = 0; }
    __syncthreads();
    int ne = min(binCnt[b * CNT_STRIDE], CAP);
    int2* src = binned + (size_t)b * CAP;
    // pass 1: per-target histogram + weighted degree (w is half in y low16)
    for (int i = tid; i < ne; i += 512) {
        int2 m = src[i];
        int cl = ((unsigned)m.x) >> 24;
        atomicAdd(&kh[cl], 1);
        unsafeAtomicAdd(&dsum[cl], __half2float(__ushort_as_half((unsigned short)(m.y & 0xFFFF))));
    }
    __syncthreads();
    // exclusive scan over 256 (threads < 256 participate)
    int v = 0;
    if (tid < BINSZ) { v = kh[tid]; ksc[tid] = v; }
    __syncthreads();
    for (int off = 1; off < BINSZ; off <<= 1) {
        int t = (tid < BINSZ && tid >= off) ? ksc[tid - off] : 0;
        __syncthreads();
        if (tid < BINSZ) ksc[tid] += t;
        __syncthreads();
    }
    if (tid < BINSZ) { kb[tid] = ksc[tid] - v; kh[tid] = 0; }
    __syncthreads();
    // pass 2: scatter into LDS at sorted position; duplicate half w -> half2
    for (int i = tid; i < ne; i += 512) {
        int2 m = src[i];
        int cl = ((unsigned)m.x) >> 24;
        int p = kb[cl] + atomicAdd(&kh[cl], 1);
        int hw = m.y & 0xFFFF;
        sE[p] = make_int2(m.x & 0xFFFFFF, hw | (hw << 16));
    }
    __syncthreads();
    // pass 3: sequential coalesced write-back, in place
    for (int i = tid; i < ne; i += 512) src[i] = sE[i];
    int node = node0 + tid;
    if (tid < BINSZ && node < N) {
        offs[node] = b * CAP + kb[tid];
        cnt[node]  = kh[tid];
        dinv[node] = rsqrtf(1.0f + dsum[tid]);
    }
}

// ---- one-time padded W^T fp16 prep (row stride LDW) ------------------------
__global__ void wt_prep(const float* __restrict__ W, _Float16* __restrict__ Wt) {
    int i = blockIdx.x * 256 + threadIdx.x;   // i < 16384
    int n = i >> 7, k = i & 127;
    Wt[(size_t)n * LDW + k] = (_Float16)W[(size_t)k * FEAT + n];
}

// ---- Y(fp16) = dinv[:,None]*(X @ W) via MFMA; TIn = float or __half --------
template<typename TIn>
__global__ __launch_bounds__(256) void gemm_mfma(const TIn* __restrict__ X,
                                                 const _Float16* __restrict__ Wt,
                                                 const float* __restrict__ dinv,
                                                 __half* __restrict__ Y, int N) {
    __shared__ _Float16 sWt[FEAT * LDW];   // 34816 B
    int tid  = threadIdx.x;
    int row0 = blockIdx.x * 128;
    {
        const int4* src = (const int4*)Wt;
        int4* dst = (int4*)sWt;
        for (int i = tid; i < (FEAT * LDW) / 8; i += 256) dst[i] = src[i];
    }
    __syncthreads();

    int wave = tid >> 6;
    int lane = tid & 63;
    int m    = lane & 15;
    int quad = lane >> 4;

    f32x4 acc[2][8];
    #pragma unroll
    for (int rt = 0; rt < 2; ++rt)
        #pragma unroll
        for (int ct = 0; ct < 8; ++ct)
            acc[rt][ct] = (f32x4){0.f, 0.f, 0.f, 0.f};

    int rowA[2];
    rowA[0] = min(row0 + wave * 32 + m, N - 1);
    rowA[1] = min(row0 + wave * 32 + 16 + m, N - 1);

    #pragma unroll
    for (int kt = 0; kt < 4; ++kt) {
        int k0 = kt * 32;
        half8 a[2];
        #pragma unroll
        for (int rt = 0; rt < 2; ++rt) {
            if constexpr (sizeof(TIn) == 4) {
                const float4* p = (const float4*)((const float*)X + (size_t)rowA[rt] * FEAT + k0 + quad * 8);
                float4 f0 = p[0], f1 = p[1];
                half8 h;
                h[0] = (_Float16)f0.x; h[1] = (_Float16)f0.y;
                h[2] = (_Float16)f0.z; h[3] = (_Float16)f0.w;
                h[4] = (_Float16)f1.x; h[5] = (_Float16)f1.y;
                h[6] = (_Float16)f1.z; h[7] = (_Float16)f1.w;
                a[rt] = h;
            } else {
                a[rt] = *(const half8*)((const _Float16*)X + (size_t)rowA[rt] * FEAT + k0 + quad * 8);
            }
        }
        #pragma unroll
        for (int ct = 0; ct < 8; ++ct) {
            half8 b = *(const half8*)&sWt[(ct * 16 + m) * LDW + k0 + quad * 8];
            acc[0][ct] = __builtin_amdgcn_mfma_f32_16x16x32_f16(a[0], b, acc[0][ct], 0, 0, 0);
            acc[1][ct] = __builtin_amdgcn_mfma_f32_16x16x32_f16(a[1], b, acc[1][ct], 0, 0, 0);
        }
    }

    #pragma unroll
    for (int rt = 0; rt < 2; ++rt) {
        int lr0 = wave * 32 + rt * 16 + quad * 4;
        #pragma unroll
        for (int r = 0; r < 4; ++r) {
            int gr = row0 + lr0 + r;
            if (gr < N) {
                float d = dinv[gr];
                #pragma unroll
                for (int ct = 0; ct < 8; ++ct)
                    Y[(size_t)gr * FEAT + ct * 16 + m] = __float2half(d * acc[rt][ct][r]);
            }
        }
    }
}

// ---- per-node aggregation (CSR): 4 rows/gather, fp16 out; node-range split -
__global__ __launch_bounds__(256) void agg_kernel(const __half* __restrict__ Y,
                                                  const int2* __restrict__ elist,
                                                  const int* __restrict__ offs,
                                                  const int* __restrict__ cnt,
                                                  const float* __restrict__ dinv,
                                                  const float* __restrict__ bias,
                                                  __half* __restrict__ Out,
                                                  int node0g, int nodeEnd) {
    int node = node0g + blockIdx.x * 4 + (threadIdx.x >> 6);
    int lane = threadIdx.x & 63;
    if (node >= nodeEnd) return;
    int grp = lane >> 4;       // replica / edge slot within group-of-4
    int fl  = lane & 15;       // feature block: feats [fl*8, fl*8+8)
    int c = cnt[node];
    const int2* meta = elist + offs[node];

    __half2 z = __floats2half2_rn(0.f, 0.f);
    __half2 a0 = z, a1 = z, a2 = z, a3 = z;
    __half2 b0 = z, b1 = z, b2 = z, b3 = z;

    // self-loop term (weight 1): only replica group 0 contributes it
    if (grp == 0) {
        int4 sv = ((const int4*)(Y + (size_t)node * FEAT))[fl];
        a0 = *(const __half2*)&sv.x; a1 = *(const __half2*)&sv.y;
        a2 = *(const __half2*)&sv.z; a3 = *(const __half2*)&sv.w;
    }

    for (int t = 0; t < c; t += 8) {
        int eA = t + grp;
        int eB = t + 4 + grp;
        int2 mA = (eA < c) ? meta[eA] : make_int2(node, 0);  // w=0 pad, safe row
        int2 mB = (eB < c) ? meta[eB] : make_int2(node, 0);
        int4 vA = *(const int4*)(Y + (size_t)mA.x * FEAT + fl * 8);
        int4 vB = *(const int4*)(Y + (size_t)mB.x * FEAT + fl * 8);
        __half2 wA = *(const __half2*)&mA.y;
        __half2 wB = *(const __half2*)&mB.y;
        a0 = __hfma2(wA, *(const __half2*)&vA.x, a0);
        a1 = __hfma2(wA, *(const __half2*)&vA.y, a1);
        a2 = __hfma2(wA, *(const __half2*)&vA.z, a2);
        a3 = __hfma2(wA, *(const __half2*)&vA.w, a3);
        b0 = __hfma2(wB, *(const __half2*)&vB.x, b0);
        b1 = __hfma2(wB, *(const __half2*)&vB.y, b1);
        b2 = __hfma2(wB, *(const __half2*)&vB.z, b2);
        b3 = __hfma2(wB, *(const __half2*)&vB.w, b3);
    }

    float2 F0 = __half22float2(a0), F1 = __half22float2(a1);
    float2 F2 = __half22float2(a2), F3 = __half22float2(a3);
    {
        float2 t0 = __half22float2(b0), t1 = __half22float2(b1);
        float2 t2 = __half22float2(b2), t3 = __half22float2(b3);
        F0.x += t0.x; F0.y += t0.y; F1.x += t1.x; F1.y += t1.y;
        F2.x += t2.x; F2.y += t2.y; F3.x += t3.x; F3.y += t3.y;
    }
    float f[8] = {F0.x, F0.y, F1.x, F1.y, F2.x, F2.y, F3.x, F3.y};
    #pragma unroll
    for (int i = 0; i < 8; ++i) {
        f[i] += __shfl_xor(f[i], 16);
        f[i] += __shfl_xor(f[i], 32);
    }
    if (grp == 0) {
        float d = dinv[node];
        int c0 = fl * 8;
        float4 bo0 = *(const float4*)(bias + c0);
        float4 bo1 = *(const float4*)(bias + c0 + 4);
        __half2 p01 = __floats2half2_rn(fmaxf(d * f[0] + bo0.x, 0.f), fmaxf(d * f[1] + bo0.y, 0.f));
        __half2 p23 = __floats2half2_rn(fmaxf(d * f[2] + bo0.z, 0.f), fmaxf(d * f[3] + bo0.w, 0.f));
        __half2 p45 = __floats2half2_rn(fmaxf(d * f[4] + bo1.x, 0.f), fmaxf(d * f[5] + bo1.y, 0.f));
        __half2 p67 = __floats2half2_rn(fmaxf(d * f[6] + bo1.z, 0.f), fmaxf(d * f[7] + bo1.w, 0.f));
        iv4 ov = { *(int*)&p01, *(int*)&p23, *(int*)&p45, *(int*)&p67 };
        *(iv4*)(Out + (size_t)node * FEAT + c0) = ov;
    }
}

// ---- pooling (batch sorted): fp16 reads, fp32 accumulate -------------------
__global__ void pool_kernel(const __half* __restrict__ H, const int* __restrict__ batch,
                            float* __restrict__ pooled, int N, int chunk) {
    int f  = threadIdx.x;
    int n0 = blockIdx.x * chunk;
    if (n0 >= N) return;
    int n1 = min(n0 + chunk, N);
    float acc = 0.f;
    int cur = batch[n0];
    for (int n = n0; n < n1; ++n) {
        int g = batch[n];
        if (g != cur) {
            unsafeAtomicAdd(&pooled[cur * FEAT + f], acc);
            acc = 0.f;
            cur = g;
        }
        acc += __half2float(H[(size_t)n * FEAT + f]);
    }
    unsafeAtomicAdd(&pooled[cur * FEAT + f], acc);
}

// ---- classifier ------------------------------------------------------------
__global__ void classify_kernel(const float* __restrict__ pooled, const float* __restrict__ Wc,
                                const float* __restrict__ bc, float* __restrict__ out) {
    int g = blockIdx.x;
    int c = threadIdx.x;
    float acc = bc[c];
    const float* pr = pooled + g * FEAT;
    for (int k = 0; k < FEAT; ++k) acc += pr[k] * Wc[k * OUTC + c];
    out[g * OUTC + c] = 1.0f / (1.0f + expf(-acc));
}

extern "C" void kernel_launch(void* const* d_in, const int* in_sizes, int n_in,
                              void* d_out, int out_size, void* d_ws, size_t ws_size,
                              hipStream_t stream) {
    const float* x     = (const float*)d_in[0];
    const int*   ei    = (const int*)d_in[1];
    const float* ew    = (const float*)d_in[2];
    const int*   batch = (const int*)d_in[3];
    const float* W1    = (const float*)d_in[4];
    const float* b1    = (const float*)d_in[5];
    const float* W2    = (const float*)d_in[6];
    const float* b2    = (const float*)d_in[7];
    const float* Wc    = (const float*)d_in[8];
    const float* bc    = (const float*)d_in[9];
    float* out = (float*)d_out;

    const int N = in_sizes[0] / FEAT;
    const int E = in_sizes[2];
    const int G = out_size / OUTC;
    const int nbins = (N + BINSZ - 1) / BINSZ;

    char* w = (char*)d_ws;
    size_t off = 0;
    auto alloc = [&](size_t bytes) {
        void* p = w + off;
        off = (off + bytes + 255) & ~(size_t)255;
        return p;
    };
    float*     dinv   = (float*)alloc((size_t)N * 4);
    int*       cnt    = (int*)alloc((size_t)N * 4);
    int*       offs   = (int*)alloc((size_t)N * 4);
    int*       binCnt = (int*)alloc((size_t)nbins * CNT_STRIDE * 4);  // line-padded
    int2*      binned = (int2*)alloc((size_t)nbins * CAP * 8);  // ~28.8 MB (sorted in place)
    __half*    bufY   = (__half*)alloc((size_t)N * FEAT * 2);   // fp16 Y
    __half*    bufH   = (__half*)alloc((size_t)N * FEAT * 2);   // fp16 h
    float*     pooled = (float*)alloc((size_t)G * FEAT * 4);
    _Float16*  wt1    = (_Float16*)alloc((size_t)FEAT * LDW * 2);
    _Float16*  wt2    = (_Float16*)alloc((size_t)FEAT * LDW * 2);
    (void)ws_size;

    hipMemsetAsync(binCnt, 0, (size_t)nbins * CNT_STRIDE * 4, stream);
    hipMemsetAsync(pooled, 0, (size_t)G * FEAT * 4, stream);

    bin_edges<<<(E + TILE_A - 1) / TILE_A, 512, (size_t)TILE_A * sizeof(int2), stream>>>(ei, ew, binCnt, binned, E, nbins);
    bin_sort_csr<<<nbins, 512, (size_t)CAP * sizeof(int2), stream>>>(binned, binCnt, offs, cnt, dinv, N);
    wt_prep<<<64, 256, 0, stream>>>(W1, wt1);
    wt_prep<<<64, 256, 0, stream>>>(W2, wt2);

    const int gemm_blocks = (N + 127) / 128;
    const int half = (N + 1) / 2;               // node-range split (R21)
    const int aggA = (half + 3) / 4;
    const int aggB = (N - half + 3) / 4;

    gemm_mfma<float><<<gemm_blocks, 256, 0, stream>>>(x, wt1, dinv, bufY, N);
    agg_kernel<<<aggA, 256, 0, stream>>>(bufY, binned, offs, cnt, dinv, b1, bufH, 0, half);
    agg_kernel<<<aggB, 256, 0, stream>>>(bufY, binned, offs, cnt, dinv, b1, bufH, half, N);
    gemm_mfma<__half><<<gemm_blocks, 256, 0, stream>>>(bufH, wt2, dinv, bufY, N);
    agg_kernel<<<aggA, 256, 0, stream>>>(bufY, binned, offs, cnt, dinv, b2, bufH, 0, half);
    agg_kernel<<<aggB, 256, 0, stream>>>(bufY, binned, offs, cnt, dinv, b2, bufH, half, N);

    const int chunk = 128;
    pool_kernel<<<(N + chunk - 1) / chunk, FEAT, 0, stream>>>(bufH, batch, pooled, N, chunk);
    classify_kernel<<<G, OUTC, 0, stream>>>(pooled, Wc, bc, out);
}